// Round 7
// baseline (585.843 us; speedup 1.0000x reference)
//
#include <hip/hip_runtime.h>
#include <hip/hip_bf16.h>

#define NB 32768
#define NSLOT 64
#define EPS 1e-5f

using bf16 = __hip_bfloat16;

// ---------- storage-type helpers (f32 or bf16 workspace) ----------
template<typename TY> __device__ __forceinline__ float ldF(const TY* p, size_t i);
template<> __device__ __forceinline__ float ldF<float>(const float* p, size_t i){ return p[i]; }
template<> __device__ __forceinline__ float ldF<bf16 >(const bf16*  p, size_t i){ return __bfloat162float(p[i]); }
template<typename TY> __device__ __forceinline__ void stF(TY* p, size_t i, float v);
template<> __device__ __forceinline__ void stF<float>(float* p, size_t i, float v){ p[i] = v; }
template<> __device__ __forceinline__ void stF<bf16 >(bf16*  p, size_t i, float v){ p[i] = __float2bfloat16(v); }

// y workspace layout (per tau, per sample): slot = k*64 + tg*16 + o, t = 4*k + tg.
// Lane l = tg*16+o stores slot k*64+l -> contiguous 256B wave stores (128B for k=4).

// weight-LDS word offsets. Transposed layouts: per o, row per tap, 12 c-values
// contiguous (3x float4 reads). Padded o-strides (100/44/68) => 16B-aligned rows
// and o-lanes spread across bank quads (2-way max aliasing = free).
#define OFF_W1 0       // t1w1T [16][100]: [o][k*12+c], 72 used
#define OFF_W2 1600    // t2w1T [16][44]:  [o][k*12+c], 36 used
#define OFF_W3 2304    // c1w1T [16][68]:  [o][kh*12+d], 57 used
#define OFF_C0 3392    // c0wT  [9][12]:   [d][c]
#define OFF_B1 3500
#define OFF_B2 3516
#define OFF_B3 3532
#define OFF_C0B 3548   // 9
#define WL_SIZE 3557

#define FMA12(acc, e, wA, wB, wC) { \
    const float4 x0 = *reinterpret_cast<const float4*>(e); \
    const float4 x1 = *reinterpret_cast<const float4*>((e) + 4); \
    const float4 x2 = *reinterpret_cast<const float4*>((e) + 8); \
    acc = fmaf(x0.x, wA.x, acc); acc = fmaf(x0.y, wA.y, acc); \
    acc = fmaf(x0.z, wA.z, acc); acc = fmaf(x0.w, wA.w, acc); \
    acc = fmaf(x1.x, wB.x, acc); acc = fmaf(x1.y, wB.y, acc); \
    acc = fmaf(x1.z, wB.z, acc); acc = fmaf(x1.w, wB.w, acc); \
    acc = fmaf(x2.x, wC.x, acc); acc = fmaf(x2.y, wC.y, acc); \
    acc = fmaf(x2.z, wC.z, acc); acc = fmaf(x2.w, wC.w, acc); }

#define FMA9(acc, e, wA, wB, w8v) { \
    const float4 x0 = *reinterpret_cast<const float4*>(e); \
    const float4 x1 = *reinterpret_cast<const float4*>((e) + 4); \
    const float  x2 = (e)[8]; \
    acc = fmaf(x0.x, wA.x, acc); acc = fmaf(x0.y, wA.y, acc); \
    acc = fmaf(x0.z, wA.z, acc); acc = fmaf(x0.w, wA.w, acc); \
    acc = fmaf(x1.x, wB.x, acc); acc = fmaf(x1.y, wB.y, acc); \
    acc = fmaf(x1.z, wB.z, acc); acc = fmaf(x1.w, wB.w, acc); \
    acc = fmaf(x2, w8v, acc); }

// ---------------- Kernel A: MLP + xcorr + first convs + BN1 stats ----------------
template<typename TY>
__global__ __launch_bounds__(256)
void kA(const float* __restrict__ raw, const float* __restrict__ eegf,
        const float* __restrict__ fgw1, const float* __restrict__ fgb1,
        const float* __restrict__ fgw2, const float* __restrict__ fgb2,
        const float* __restrict__ t1w1, const float* __restrict__ t1b1,
        const float* __restrict__ t2w1, const float* __restrict__ t2b1,
        const float* __restrict__ c0w,  const float* __restrict__ c0b,
        const float* __restrict__ c1w1, const float* __restrict__ c1b1,
        TY* __restrict__ yws, float* __restrict__ stat1)
{
    // eeg2[s]: phase 1 = staged raw (756 w); phase 2 = eeg transposed [t][16]
    // (912 w, 12 used per row); phase 3 = ec [t][12] (684 w, 9 used per row).
    __shared__ float eeg2[4][912];
    __shared__ float wl[WL_SIZE];
    __shared__ float h35_s[4][36];
    __shared__ float filt_s[4][8];
    __shared__ float stat_s[96];

    const int tid = threadIdx.x;
    const int l   = tid & 63;
    const int s   = tid >> 6;
    const int gs  = blockIdx.x * 4 + s;

    if (tid < 96) stat_s[tid] = 0.f;
    // ---- stage transposed weights (once per block) ----
    for (int idx = tid; idx < 1152; idx += 256) { int o = idx / 72, r = idx % 72, c = r / 6, k = r % 6; wl[OFF_W1 + o * 100 + k * 12 + c] = t1w1[idx]; }
    for (int idx = tid; idx < 576;  idx += 256) { int o = idx / 36, r = idx % 36, c = r / 3, k = r % 3; wl[OFF_W2 + o * 44 + k * 12 + c] = t2w1[idx]; }
    for (int idx = tid; idx < 720;  idx += 256) { int o = idx / 45, r = idx % 45, kh = r / 9, d = r % 9; wl[OFF_W3 + o * 68 + kh * 12 + d] = c1w1[idx]; }
    for (int idx = tid; idx < 108;  idx += 256) { int c = idx / 9, d = idx % 9; wl[OFF_C0 + d * 12 + c] = c0w[idx]; }
    if (tid < 16) { wl[OFF_B1 + tid] = t1b1[tid]; wl[OFF_B2 + tid] = t2b1[tid]; wl[OFF_B3 + tid] = c1b1[tid]; }
    if (tid < 9)  wl[OFF_C0B + tid] = c0b[tid];
    // ---- stage raw into eeg2 region (per wave, coalesced) ----
    float* rawS = &eeg2[s][0];
    for (int r = l; r < 756; r += 64)
        rawS[r] = raw[(size_t)gs * 756 + r];
    __syncthreads();

    // ---- MLP: h35 = tanh(eegf @ fg_w1 + b1) ----
    if (l < 35) {
        const float* e = eegf + (size_t)gs * 168;
        float a0 = 0.f, a1 = 0.f, a2 = 0.f, a3 = 0.f;
        #pragma unroll 2
        for (int i = 0; i < 168; i += 4) {
            a0 = fmaf(e[i],     fgw1[i * 35 + l],       a0);
            a1 = fmaf(e[i + 1], fgw1[(i + 1) * 35 + l], a1);
            a2 = fmaf(e[i + 2], fgw1[(i + 2) * 35 + l], a2);
            a3 = fmaf(e[i + 3], fgw1[(i + 3) * 35 + l], a3);
        }
        h35_s[s][l] = tanhf(a0 + a1 + a2 + a3 + fgb1[l]);
    }
    __syncthreads();
    // ---- filt = tanh(h35 @ fg_w2 + b2) ----
    if (l < 7) {
        float a = fgb2[l];
        for (int j = 0; j < 35; ++j) a = fmaf(h35_s[s][j], fgw2[j * 7 + l], a);
        filt_s[s][l] = tanhf(a);
    }
    __syncthreads();

    float* eegS = &eeg2[s][0];

    // ---- xcorr into registers, then write transposed [t][16] ----
    // lane handles m = l + 64j: t = m>>4, c = m&15 (c<12 valid, pads get 0).
    {
        const float f0 = filt_s[s][0], f1 = filt_s[s][1], f2 = filt_s[s][2],
                    f3 = filt_s[s][3], f4v = filt_s[s][4], f5 = filt_s[s][5], f6 = filt_s[s][6];
        #define XC(j, v) float v = 0.f; { int m = l + 64 * (j); int tt = m >> 4, cc = m & 15; \
            if (cc < 12) { const float* rp = rawS + cc * 63 + tt; \
                v = rp[0] * f0; v = fmaf(rp[1], f1, v); v = fmaf(rp[2], f2, v); v = fmaf(rp[3], f3, v); \
                v = fmaf(rp[4], f4v, v); v = fmaf(rp[5], f5, v); v = fmaf(rp[6], f6, v); } }
        XC(0, v0)  XC(1, v1)  XC(2, v2)  XC(3, v3)  XC(4, v4)
        XC(5, v5)  XC(6, v6)  XC(7, v7)  XC(8, v8)  XC(9, v9)
        XC(10, v10) XC(11, v11) XC(12, v12) XC(13, v13)
        float v14 = 0.f;
        if (l < 16) { int m = l + 896; int tt = m >> 4, cc = m & 15;
            if (cc < 12) { const float* rp = rawS + cc * 63 + tt;
                v14 = rp[0] * f0; v14 = fmaf(rp[1], f1, v14); v14 = fmaf(rp[2], f2, v14); v14 = fmaf(rp[3], f3, v14);
                v14 = fmaf(rp[4], f4v, v14); v14 = fmaf(rp[5], f5, v14); v14 = fmaf(rp[6], f6, v14); } }
        #undef XC
        // all reads of rawS complete (lockstep + program order) -> overwrite
        eegS[l]       = v0;  eegS[l + 64]  = v1;  eegS[l + 128] = v2;  eegS[l + 192] = v3;
        eegS[l + 256] = v4;  eegS[l + 320] = v5;  eegS[l + 384] = v6;  eegS[l + 448] = v7;
        eegS[l + 512] = v8;  eegS[l + 576] = v9;  eegS[l + 640] = v10; eegS[l + 704] = v11;
        eegS[l + 768] = v12; eegS[l + 832] = v13;
        if (l < 16) eegS[l + 896] = v14;
    }

    const int o = l & 15, tg = l >> 4;      // t = tg + 4k; k=4 valid only for tg<2
    const bool k4 = (tg < 2);

    // ---- tau=0: conv1d k=6 s=3.  row(k,kh) = 48tg + 16kh + 192k ----
    {
        const float b = wl[OFF_B1 + o];
        float a0 = b, a1 = b, a2 = b, a3 = b, a4 = b;
        const float* w1p = &wl[OFF_W1 + o * 100];
        const float* eS  = eegS + 48 * tg;
        #pragma unroll 2
        for (int kh = 0; kh < 6; ++kh) {
            const float4 wA = *reinterpret_cast<const float4*>(w1p + kh * 12);
            const float4 wB = *reinterpret_cast<const float4*>(w1p + kh * 12 + 4);
            const float4 wC = *reinterpret_cast<const float4*>(w1p + kh * 12 + 8);
            const float* e0 = eS + 16 * kh;
            FMA12(a0, e0,       wA, wB, wC);
            FMA12(a1, e0 + 192, wA, wB, wC);
            FMA12(a2, e0 + 384, wA, wB, wC);
            FMA12(a3, e0 + 576, wA, wB, wC);
            if (k4) FMA12(a4, e0 + 768, wA, wB, wC);
        }
        size_t base = (size_t)gs * 288 + l;
        stF<TY>(yws, base,       a0); stF<TY>(yws, base + 64,  a1);
        stF<TY>(yws, base + 128, a2); stF<TY>(yws, base + 192, a3);
        float sum = a0 + a1 + a2 + a3;
        float sq  = fmaf(a0, a0, fmaf(a1, a1, fmaf(a2, a2, a3 * a3)));
        if (k4) { stF<TY>(yws, base + 256, a4); sum += a4; sq = fmaf(a4, a4, sq); }
        sum += __shfl_xor(sum, 16); sq += __shfl_xor(sq, 16);
        sum += __shfl_xor(sum, 32); sq += __shfl_xor(sq, 32);
        if (tg == 0) { atomicAdd(&stat_s[o * 2], sum); atomicAdd(&stat_s[o * 2 + 1], sq); }
    }

    // ---- tau=1: conv1d k=3 d=2 s=3.  row(k,kh) = 48tg + 32kh + 192k ----
    {
        const float b = wl[OFF_B2 + o];
        float a0 = b, a1 = b, a2 = b, a3 = b, a4 = b;
        const float* w2p = &wl[OFF_W2 + o * 44];
        const float* eS  = eegS + 48 * tg;
        #pragma unroll 2
        for (int kh = 0; kh < 3; ++kh) {
            const float4 wA = *reinterpret_cast<const float4*>(w2p + kh * 12);
            const float4 wB = *reinterpret_cast<const float4*>(w2p + kh * 12 + 4);
            const float4 wC = *reinterpret_cast<const float4*>(w2p + kh * 12 + 8);
            const float* e0 = eS + 32 * kh;
            FMA12(a0, e0,       wA, wB, wC);
            FMA12(a1, e0 + 192, wA, wB, wC);
            FMA12(a2, e0 + 384, wA, wB, wC);
            FMA12(a3, e0 + 576, wA, wB, wC);
            if (k4) FMA12(a4, e0 + 768, wA, wB, wC);
        }
        size_t base = (size_t)NB * 288 + (size_t)gs * 288 + l;
        stF<TY>(yws, base,       a0); stF<TY>(yws, base + 64,  a1);
        stF<TY>(yws, base + 128, a2); stF<TY>(yws, base + 192, a3);
        float sum = a0 + a1 + a2 + a3;
        float sq  = fmaf(a0, a0, fmaf(a1, a1, fmaf(a2, a2, a3 * a3)));
        if (k4) { stF<TY>(yws, base + 256, a4); sum += a4; sq = fmaf(a4, a4, sq); }
        sum += __shfl_xor(sum, 16); sq += __shfl_xor(sq, 16);
        sum += __shfl_xor(sum, 32); sq += __shfl_xor(sq, 32);
        if (tg == 0) { atomicAdd(&stat_s[32 + o * 2], sum); atomicAdd(&stat_s[32 + o * 2 + 1], sq); }
    }

    // ---- ec = relu(channel-linear) into registers, overlay eeg2 as [t][12] ----
    {
        #define ECC(j, u) float u = 0.f; { int n = l + 64 * (j); int t = n / 9, d = n - 9 * t; \
            const float* cw = &wl[OFF_C0 + d * 12]; \
            const float4 wA = *reinterpret_cast<const float4*>(cw); \
            const float4 wB = *reinterpret_cast<const float4*>(cw + 4); \
            const float4 wC = *reinterpret_cast<const float4*>(cw + 8); \
            const float* e = eegS + t * 16; float a = wl[OFF_C0B + d]; \
            FMA12(a, e, wA, wB, wC); u = fmaxf(a, 0.f); }
        ECC(0, u0) ECC(1, u1) ECC(2, u2) ECC(3, u3)
        ECC(4, u4) ECC(5, u5) ECC(6, u6) ECC(7, u7)
        float u8 = 0.f;
        if (l == 0) { const float* cw = &wl[OFF_C0 + 96];
            const float4 wA = *reinterpret_cast<const float4*>(cw);
            const float4 wB = *reinterpret_cast<const float4*>(cw + 4);
            const float4 wC = *reinterpret_cast<const float4*>(cw + 8);
            const float* e = eegS + 56 * 16; float a = wl[OFF_C0B + 8];
            FMA12(a, e, wA, wB, wC); u8 = fmaxf(a, 0.f); }
        #undef ECC
        // all eeg reads done -> overwrite region as ec[t*12+d]
        #define ECW(j, u) { int n = l + 64 * (j); int t = n / 9; eegS[n + 3 * t] = u; }
        ECW(0, u0) ECW(1, u1) ECW(2, u2) ECW(3, u3)
        ECW(4, u4) ECW(5, u5) ECW(6, u6) ECW(7, u7)
        if (l == 0) eegS[512 + 168] = u8;   // n=512, t=56 -> 512+3*56
        #undef ECW
    }

    // ---- tau=2: conv2d 5x9 stride (3,1).  row(k,kh) = (3tg+kh)*12 + 144k ----
    {
        const float b = wl[OFF_B3 + o];
        float a0 = b, a1 = b, a2 = b, a3 = b, a4 = b;
        const float* w3p = &wl[OFF_W3 + o * 68];
        const float* eS  = eegS + 36 * tg;
        #pragma unroll 2
        for (int kh = 0; kh < 5; ++kh) {
            const float4 wA = *reinterpret_cast<const float4*>(w3p + kh * 12);
            const float4 wB = *reinterpret_cast<const float4*>(w3p + kh * 12 + 4);
            const float  w8 = (w3p + kh * 12)[8];
            const float* e0 = eS + 12 * kh;
            FMA9(a0, e0,       wA, wB, w8);
            FMA9(a1, e0 + 144, wA, wB, w8);
            FMA9(a2, e0 + 288, wA, wB, w8);
            FMA9(a3, e0 + 432, wA, wB, w8);
            if (k4) FMA9(a4, e0 + 576, wA, wB, w8);
        }
        size_t base = (size_t)2 * NB * 288 + (size_t)gs * 288 + l;
        stF<TY>(yws, base,       a0); stF<TY>(yws, base + 64,  a1);
        stF<TY>(yws, base + 128, a2); stF<TY>(yws, base + 192, a3);
        float sum = a0 + a1 + a2 + a3;
        float sq  = fmaf(a0, a0, fmaf(a1, a1, fmaf(a2, a2, a3 * a3)));
        if (k4) { stF<TY>(yws, base + 256, a4); sum += a4; sq = fmaf(a4, a4, sq); }
        sum += __shfl_xor(sum, 16); sq += __shfl_xor(sq, 16);
        sum += __shfl_xor(sum, 32); sq += __shfl_xor(sq, 32);
        if (tg == 0) { atomicAdd(&stat_s[64 + o * 2], sum); atomicAdd(&stat_s[64 + o * 2 + 1], sq); }
    }
    __syncthreads();
    if (tid < 96) atomicAdd(&stat1[(blockIdx.x & (NSLOT - 1)) * 96 + tid], stat_s[tid]);
}

// ---------------- BN finalize (stage 1 or 2) ----------------
__global__ void kBN(const float* __restrict__ statp,
                    const float* __restrict__ g0, const float* __restrict__ be0,
                    const float* __restrict__ g1, const float* __restrict__ be1,
                    const float* __restrict__ g2, const float* __restrict__ be2,
                    float nInv, float* __restrict__ bnp)
{
    int tid = threadIdx.x;
    if (tid >= 48) return;
    int tau = tid / 16, o = tid % 16;
    float sum = 0.f, sq = 0.f;
    for (int sl = 0; sl < NSLOT; ++sl) {
        sum += statp[sl * 96 + tid * 2];
        sq  += statp[sl * 96 + tid * 2 + 1];
    }
    float mean = sum * nInv;
    float var  = sq * nInv - mean * mean;
    const float* g  = (tau == 0) ? g0 : (tau == 1) ? g1 : g2;
    const float* be = (tau == 0) ? be0 : (tau == 1) ? be1 : be2;
    float scale = g[o] / sqrtf(var + EPS);
    float shift = be[o] - mean * scale;
    bnp[tid * 2]     = scale;
    bnp[tid * 2 + 1] = shift;
}

// ---------------- Kernel C: BN1+relu, second convs, BN2 stats ----------------
template<typename TY>
__global__ __launch_bounds__(256)
void kC(const TY* __restrict__ yws, const float* __restrict__ bn1,
        const float* __restrict__ t1w2, const float* __restrict__ t1b2,
        const float* __restrict__ t2w2, const float* __restrict__ t2b2,
        const float* __restrict__ c1w2, const float* __restrict__ c1b2,
        TY* __restrict__ zws, float* __restrict__ stat2)
{
    __shared__ float h_s[3][4][288];
    __shared__ float z_s[3][4][80];
    __shared__ float bnp[96];
    const int tid = threadIdx.x;
    const int s0  = blockIdx.x * 4;

    if (tid < 96) bnp[tid] = bn1[tid];
    __syncthreads();

    for (int idx = tid; idx < 3456; idx += 256) {
        int tau = idx / 1152, rem = idx % 1152, s = rem / 288, slot = rem % 288;
        int k = slot >> 6, rr = slot & 63, tg = rr >> 4, o = rr & 15;
        int t = 4 * k + tg;
        float v = ldF<TY>(yws, (size_t)tau * NB * 288 + (size_t)(s0 + s) * 288 + slot);
        h_s[tau][s][o * 18 + t] = fmaxf(fmaf(v, bnp[(tau * 16 + o) * 2], bnp[(tau * 16 + o) * 2 + 1]), 0.f);
    }
    __syncthreads();

    for (int idx = tid; idx < 960; idx += 256) {
        int tau = idx / 320, rem = idx % 320, s = rem / 80, r = rem % 80;
        int o = r / 5, t = r % 5;
        float a;
        if (tau == 0) {
            a = t1b2[o];
            for (int c = 0; c < 16; ++c) {
                const float* hp = &h_s[0][s][c * 18 + 3 * t];
                const float* wp = &t1w2[o * 96 + c * 6];
                #pragma unroll
                for (int k = 0; k < 6; ++k) a = fmaf(hp[k], wp[k], a);
            }
        } else if (tau == 1) {
            a = t2b2[o];
            for (int c = 0; c < 16; ++c) {
                const float* hp = &h_s[1][s][c * 18 + 3 * t];
                const float* wp = &t2w2[o * 48 + c * 3];
                #pragma unroll
                for (int k = 0; k < 3; ++k) a = fmaf(hp[2 * k], wp[k], a);
            }
        } else {
            a = c1b2[o];
            for (int c = 0; c < 16; ++c) {
                const float* hp = &h_s[2][s][c * 18 + 3 * t];
                const float* wp = &c1w2[o * 80 + c * 5];
                #pragma unroll
                for (int k = 0; k < 5; ++k) a = fmaf(hp[k], wp[k], a);
            }
        }
        z_s[tau][s][r] = a;
    }
    __syncthreads();

    if (tid < 96) {
        int tau = tid / 32, rem = tid % 32, o = rem >> 1, st = rem & 1;
        float acc = 0.f;
        for (int s = 0; s < 4; ++s)
            for (int t = 0; t < 5; ++t) {
                float v = z_s[tau][s][o * 5 + t];
                acc += st ? v * v : v;
            }
        atomicAdd(&stat2[(blockIdx.x & (NSLOT - 1)) * 96 + tid], acc);
    }
    for (int idx = tid; idx < 960; idx += 256) {
        int tau = idx / 320, rem = idx % 320, s = rem / 80, r = rem % 80;
        stF<TY>(zws, (size_t)tau * NB * 80 + (size_t)(s0 + s) * 80 + r, z_s[tau][s][r]);
    }
}

// ---------------- Kernel E: BN2+relu, feats, FC, tanh ----------------
template<typename TY>
__global__ __launch_bounds__(256)
void kE(const TY* __restrict__ zws, const float* __restrict__ bn2,
        const float* __restrict__ fcw, const float* __restrict__ fcb,
        float* __restrict__ out)
{
    __shared__ float fcw_s[160 * 50];
    __shared__ float feats[8][320];
    __shared__ float fcb_s[50];
    __shared__ float bnp[96];
    const int tid = threadIdx.x;
    const int s0  = blockIdx.x * 8;

    for (int idx = tid; idx < 8000; idx += 256) fcw_s[idx] = fcw[idx];
    if (tid < 50) fcb_s[tid] = fcb[tid];
    if (tid >= 64 && tid < 160) bnp[tid - 64] = bn2[tid - 64];
    __syncthreads();

    for (int idx = tid; idx < 8 * 320; idx += 256) {
        int s = idx / 320, f = idx % 320;
        int g = f / 80; int tau = (g == 3) ? 2 : g;
        int r = f % 80, o = r / 5;
        float v = ldF<TY>(zws, (size_t)tau * NB * 80 + (size_t)(s0 + s) * 80 + r);
        feats[s][f] = fmaxf(fmaf(v, bnp[(tau * 16 + o) * 2], bnp[(tau * 16 + o) * 2 + 1]), 0.f);
    }
    __syncthreads();

    float accA = 0.f, accB = 0.f;
    int sA = tid / 50, uA = tid % 50;
    int iB = tid + 256, sB = iB / 50, uB = iB % 50;
    if (tid < 400) {
        accA = fcb_s[uA];
        for (int f = 0; f < 160; ++f) accA = fmaf(feats[sA][f], fcw_s[f * 50 + uA], accA);
    }
    if (tid < 144) {
        accB = fcb_s[uB];
        for (int f = 0; f < 160; ++f) accB = fmaf(feats[sB][f], fcw_s[f * 50 + uB], accB);
    }
    __syncthreads();
    for (int idx = tid; idx < 8000; idx += 256) fcw_s[idx] = fcw[8000 + idx];
    __syncthreads();
    if (tid < 400) {
        for (int f = 0; f < 160; ++f) accA = fmaf(feats[sA][160 + f], fcw_s[f * 50 + uA], accA);
        out[(size_t)(s0 + sA) * 50 + uA] = tanhf(accA);
    }
    if (tid < 144) {
        for (int f = 0; f < 160; ++f) accB = fmaf(feats[sB][160 + f], fcw_s[f * 50 + uB], accB);
        out[(size_t)(s0 + sB) * 50 + uB] = tanhf(accB);
    }
}

// ---------------- host launcher ----------------
template<typename TY>
static void launch_all(void* const* d_in, void* d_out, void* d_ws, hipStream_t stream)
{
    const float* raw  = (const float*)d_in[0];
    const float* eegf = (const float*)d_in[1];
    const float* fgw1 = (const float*)d_in[2];
    const float* fgb1 = (const float*)d_in[3];
    const float* fgw2 = (const float*)d_in[4];
    const float* fgb2 = (const float*)d_in[5];
    const float* t1w1 = (const float*)d_in[6];
    const float* t1b1 = (const float*)d_in[7];
    const float* t1g1 = (const float*)d_in[8];
    const float* t1be1= (const float*)d_in[9];
    const float* t1w2 = (const float*)d_in[10];
    const float* t1b2 = (const float*)d_in[11];
    const float* t1g2 = (const float*)d_in[12];
    const float* t1be2= (const float*)d_in[13];
    const float* t2w1 = (const float*)d_in[14];
    const float* t2b1 = (const float*)d_in[15];
    const float* t2g1 = (const float*)d_in[16];
    const float* t2be1= (const float*)d_in[17];
    const float* t2w2 = (const float*)d_in[18];
    const float* t2b2 = (const float*)d_in[19];
    const float* t2g2 = (const float*)d_in[20];
    const float* t2be2= (const float*)d_in[21];
    const float* c0w  = (const float*)d_in[22];
    const float* c0b  = (const float*)d_in[23];
    const float* c1w1 = (const float*)d_in[24];
    const float* c1b1 = (const float*)d_in[25];
    const float* c1g1 = (const float*)d_in[26];
    const float* c1be1= (const float*)d_in[27];
    const float* c1w2 = (const float*)d_in[28];
    const float* c1b2 = (const float*)d_in[29];
    const float* c1g2 = (const float*)d_in[30];
    const float* c1be2= (const float*)d_in[31];
    const float* fcw  = (const float*)d_in[32];
    const float* fcb  = (const float*)d_in[33];

    char* ws = (char*)d_ws;
    TY* yws = (TY*)ws;
    TY* zws = (TY*)(ws + (size_t)3 * NB * 288 * sizeof(TY));
    float* stat1 = (float*)(ws + (size_t)3 * NB * 288 * sizeof(TY) + (size_t)3 * NB * 80 * sizeof(TY));
    float* stat2 = stat1 + NSLOT * 96;
    float* bn1   = stat2 + NSLOT * 96;
    float* bn2   = bn1 + 96;

    hipMemsetAsync(stat1, 0, 2 * NSLOT * 96 * sizeof(float), stream);

    kA<TY><<<NB / 4, 256, 0, stream>>>(raw, eegf, fgw1, fgb1, fgw2, fgb2,
                                       t1w1, t1b1, t2w1, t2b1, c0w, c0b, c1w1, c1b1,
                                       yws, stat1);
    kBN<<<1, 64, 0, stream>>>(stat1, t1g1, t1be1, t2g1, t2be1, c1g1, c1be1,
                              1.f / (float)((size_t)NB * 18), bn1);
    kC<TY><<<NB / 4, 256, 0, stream>>>(yws, bn1, t1w2, t1b2, t2w2, t2b2, c1w2, c1b2,
                                       zws, stat2);
    kBN<<<1, 64, 0, stream>>>(stat2, t1g2, t1be2, t2g2, t2be2, c1g2, c1be2,
                              1.f / (float)((size_t)NB * 5), bn2);
    kE<TY><<<NB / 8, 256, 0, stream>>>(zws, bn2, fcw, fcb, (float*)d_out);
}

extern "C" void kernel_launch(void* const* d_in, const int* in_sizes, int n_in,
                              void* d_out, int out_size, void* d_ws, size_t ws_size,
                              hipStream_t stream)
{
    (void)in_sizes; (void)n_in; (void)out_size;
    size_t statBytes = (2 * NSLOT * 96 + 192) * sizeof(float);
    size_t needF32 = ((size_t)3 * NB * 288 + (size_t)3 * NB * 80) * 4 + statBytes;
    if (ws_size >= needF32)
        launch_all<float>(d_in, d_out, d_ws, stream);
    else
        launch_all<bf16>(d_in, d_out, d_ws, stream);
}

// Round 8
// 499.310 us; speedup vs baseline: 1.1733x; 1.1733x over previous
//
#include <hip/hip_runtime.h>
#include <hip/hip_bf16.h>

#define NB 32768
#define NSLOT 64
#define EPS 1e-5f

using bf16 = __hip_bfloat16;

// ---------- storage-type helpers (f32 or bf16 workspace) ----------
template<typename TY> __device__ __forceinline__ float ldF(const TY* p, size_t i);
template<> __device__ __forceinline__ float ldF<float>(const float* p, size_t i){ return p[i]; }
template<> __device__ __forceinline__ float ldF<bf16 >(const bf16*  p, size_t i){ return __bfloat162float(p[i]); }
template<typename TY> __device__ __forceinline__ void stF(TY* p, size_t i, float v);
template<> __device__ __forceinline__ void stF<float>(float* p, size_t i, float v){ p[i] = v; }
template<> __device__ __forceinline__ void stF<bf16 >(bf16*  p, size_t i, float v){ p[i] = __float2bfloat16(v); }

// y workspace layout (per tau, per sample): slot = k*64 + tg*16 + o, t = 4*k + tg.
// Lane l = tg*16+o stores slot k*64+l -> contiguous 256B wave stores (128B for k=4).

// weight-LDS offsets. Transposed per-o rows, stride chosen so the 16 o-lanes'
// row starts alias at most 2-way in banks (2-way = free per m136):
//   W1 stride 76: 76%32=12 -> o*12%32 cycles 8 values, 2-way.
//   W2 stride 44: same residue 12, 2-way.  W3 stride 60: 60%32=28, 2-way.
#define OFF_W1 0       // t1w1T [16][76]: [o][kh*12+c], 72 used
#define OFF_W2 1216    // t2w1T [16][44]: [o][kh*12+c], 36 used
#define OFF_W3 1920    // c1w1T [16][60]: [o][kh*12+d], 57 used
#define OFF_C0 2880    // c0w   [12][9] original order (scalar reads)
#define OFF_B1 2988
#define OFF_B2 3004
#define OFF_B3 3020
#define OFF_C0B 3036   // 9
#define WL_SIZE 3045

#define FMA12(acc, e, wA, wB, wC) { \
    const float4 x0 = *reinterpret_cast<const float4*>(e); \
    const float4 x1 = *reinterpret_cast<const float4*>((e) + 4); \
    const float4 x2 = *reinterpret_cast<const float4*>((e) + 8); \
    acc = fmaf(x0.x, wA.x, acc); acc = fmaf(x0.y, wA.y, acc); \
    acc = fmaf(x0.z, wA.z, acc); acc = fmaf(x0.w, wA.w, acc); \
    acc = fmaf(x1.x, wB.x, acc); acc = fmaf(x1.y, wB.y, acc); \
    acc = fmaf(x1.z, wB.z, acc); acc = fmaf(x1.w, wB.w, acc); \
    acc = fmaf(x2.x, wC.x, acc); acc = fmaf(x2.y, wC.y, acc); \
    acc = fmaf(x2.z, wC.z, acc); acc = fmaf(x2.w, wC.w, acc); }

#define FMA9(acc, e, wA, wB, w8v) { \
    const float4 x0 = *reinterpret_cast<const float4*>(e); \
    const float4 x1 = *reinterpret_cast<const float4*>((e) + 4); \
    const float  x2 = (e)[8]; \
    acc = fmaf(x0.x, wA.x, acc); acc = fmaf(x0.y, wA.y, acc); \
    acc = fmaf(x0.z, wA.z, acc); acc = fmaf(x0.w, wA.w, acc); \
    acc = fmaf(x1.x, wB.x, acc); acc = fmaf(x1.y, wB.y, acc); \
    acc = fmaf(x1.z, wB.z, acc); acc = fmaf(x1.w, wB.w, acc); \
    acc = fmaf(x2, w8v, acc); }

// ---------------- Kernel A: MLP + xcorr + first convs + BN1 stats ----------------
// Wave-private phases (one wave = one sample): only 2 block barriers (wl staging,
// stat flush). eegT is a dedicated buffer so xcorr STREAMS (1 live reg, low VGPR);
// ec overlays the dead raw region with scalar reads (2-way banks = free).
template<typename TY>
__global__ __launch_bounds__(256)
void kA(const float* __restrict__ raw, const float* __restrict__ eegf,
        const float* __restrict__ fgw1, const float* __restrict__ fgb1,
        const float* __restrict__ fgw2, const float* __restrict__ fgb2,
        const float* __restrict__ t1w1, const float* __restrict__ t1b1,
        const float* __restrict__ t2w1, const float* __restrict__ t2b1,
        const float* __restrict__ c0w,  const float* __restrict__ c0b,
        const float* __restrict__ c1w1, const float* __restrict__ c1b1,
        TY* __restrict__ yws, float* __restrict__ stat1)
{
    __shared__ float raw_ec[4][756];   // raw; dead after xcorr; ec overlay [57][12]
    __shared__ float eegT[4][912];     // [t][16], c in words 0..11 (pads never read)
    __shared__ float wl[WL_SIZE];
    __shared__ float h35_s[4][36];
    __shared__ float filt_s[4][8];
    __shared__ float stat_s[96];

    const int tid = threadIdx.x;
    const int l   = tid & 63;
    const int s   = tid >> 6;
    const int gs  = blockIdx.x * 4 + s;

    if (tid < 96) stat_s[tid] = 0.f;
    // ---- stage transposed weights (once per block) ----
    for (int idx = tid; idx < 1152; idx += 256) { int o = idx / 72, r = idx % 72, c = r / 6, k = r % 6; wl[OFF_W1 + o * 76 + k * 12 + c] = t1w1[idx]; }
    for (int idx = tid; idx < 576;  idx += 256) { int o = idx / 36, r = idx % 36, c = r / 3, k = r % 3; wl[OFF_W2 + o * 44 + k * 12 + c] = t2w1[idx]; }
    for (int idx = tid; idx < 720;  idx += 256) { int o = idx / 45, r = idx % 45, kh = r / 9, d = r % 9; wl[OFF_W3 + o * 60 + kh * 12 + d] = c1w1[idx]; }
    for (int idx = tid; idx < 108;  idx += 256) wl[OFF_C0 + idx] = c0w[idx];
    if (tid < 16) { wl[OFF_B1 + tid] = t1b1[tid]; wl[OFF_B2 + tid] = t2b1[tid]; wl[OFF_B3 + tid] = c1b1[tid]; }
    if (tid < 9)  wl[OFF_C0B + tid] = c0b[tid];
    // ---- stage raw (wave-private, coalesced) ----
    float* rawS = &raw_ec[s][0];
    for (int r = l; r < 756; r += 64)
        rawS[r] = raw[(size_t)gs * 756 + r];
    __syncthreads();   // wl + stat_s visible to all waves

    // ---- MLP: h35 = tanh(eegf @ fg_w1 + b1)  (wave-synchronous, no barrier) ----
    if (l < 35) {
        const float* e = eegf + (size_t)gs * 168;
        float a0 = 0.f, a1 = 0.f, a2 = 0.f, a3 = 0.f;
        #pragma unroll 2
        for (int i = 0; i < 168; i += 4) {
            a0 = fmaf(e[i],     fgw1[i * 35 + l],       a0);
            a1 = fmaf(e[i + 1], fgw1[(i + 1) * 35 + l], a1);
            a2 = fmaf(e[i + 2], fgw1[(i + 2) * 35 + l], a2);
            a3 = fmaf(e[i + 3], fgw1[(i + 3) * 35 + l], a3);
        }
        h35_s[s][l] = tanhf(a0 + a1 + a2 + a3 + fgb1[l]);
    }
    if (l < 7) {
        float a = fgb2[l];
        for (int j = 0; j < 35; ++j) a = fmaf(h35_s[s][j], fgw2[j * 7 + l], a);
        filt_s[s][l] = tanhf(a);
    }

    float* eT = &eegT[s][0];

    // ---- xcorr, streaming: lane l owns channel c=l&15 (c<12 valid), t = (l>>4)+4j ----
    {
        const float f0 = filt_s[s][0], f1 = filt_s[s][1], f2 = filt_s[s][2],
                    f3 = filt_s[s][3], f4 = filt_s[s][4], f5 = filt_s[s][5], f6 = filt_s[s][6];
        const int cc = l & 15;
        const float* rp0 = rawS + (cc < 12 ? cc : 0) * 63;   // clamp keeps pads in-bounds
        #pragma unroll 2
        for (int j = 0; j < 14; ++j) {
            const float* rp = rp0 + (l >> 4) + 4 * j;
            float v = rp[0] * f0;
            v = fmaf(rp[1], f1, v); v = fmaf(rp[2], f2, v); v = fmaf(rp[3], f3, v);
            v = fmaf(rp[4], f4, v); v = fmaf(rp[5], f5, v); v = fmaf(rp[6], f6, v);
            eT[l + 64 * j] = v;      // == eegT[t*16 + c], coalesced
        }
        if (l < 16) {                // t = 56
            const float* rp = rp0 + 56;
            float v = rp[0] * f0;
            v = fmaf(rp[1], f1, v); v = fmaf(rp[2], f2, v); v = fmaf(rp[3], f3, v);
            v = fmaf(rp[4], f4, v); v = fmaf(rp[5], f5, v); v = fmaf(rp[6], f6, v);
            eT[l + 896] = v;
        }
    }

    const int o = l & 15, tg = l >> 4;      // t = tg + 4k; k=4 valid only for tg<2
    const bool k4 = (tg < 2);

    // ---- tau=0: conv1d k=6 s=3.  e-row = 48tg + 16kh + 192k ----
    {
        const float b = wl[OFF_B1 + o];
        float a0 = b, a1 = b, a2 = b, a3 = b, a4 = b;
        const float* w1p = &wl[OFF_W1 + o * 76];
        const float* eS  = eT + 48 * tg;
        #pragma unroll 2
        for (int kh = 0; kh < 6; ++kh) {
            const float4 wA = *reinterpret_cast<const float4*>(w1p + kh * 12);
            const float4 wB = *reinterpret_cast<const float4*>(w1p + kh * 12 + 4);
            const float4 wC = *reinterpret_cast<const float4*>(w1p + kh * 12 + 8);
            const float* e0 = eS + 16 * kh;
            FMA12(a0, e0,       wA, wB, wC);
            FMA12(a1, e0 + 192, wA, wB, wC);
            FMA12(a2, e0 + 384, wA, wB, wC);
            FMA12(a3, e0 + 576, wA, wB, wC);
            if (k4) FMA12(a4, e0 + 768, wA, wB, wC);
        }
        size_t base = (size_t)gs * 288 + l;
        stF<TY>(yws, base,       a0); stF<TY>(yws, base + 64,  a1);
        stF<TY>(yws, base + 128, a2); stF<TY>(yws, base + 192, a3);
        float sum = a0 + a1 + a2 + a3;
        float sq  = fmaf(a0, a0, fmaf(a1, a1, fmaf(a2, a2, a3 * a3)));
        if (k4) { stF<TY>(yws, base + 256, a4); sum += a4; sq = fmaf(a4, a4, sq); }
        sum += __shfl_xor(sum, 16); sq += __shfl_xor(sq, 16);
        sum += __shfl_xor(sum, 32); sq += __shfl_xor(sq, 32);
        if (tg == 0) { atomicAdd(&stat_s[o * 2], sum); atomicAdd(&stat_s[o * 2 + 1], sq); }
    }

    // ---- tau=1: conv1d k=3 d=2 s=3.  e-row = 48tg + 32kh + 192k ----
    {
        const float b = wl[OFF_B2 + o];
        float a0 = b, a1 = b, a2 = b, a3 = b, a4 = b;
        const float* w2p = &wl[OFF_W2 + o * 44];
        const float* eS  = eT + 48 * tg;
        #pragma unroll 2
        for (int kh = 0; kh < 3; ++kh) {
            const float4 wA = *reinterpret_cast<const float4*>(w2p + kh * 12);
            const float4 wB = *reinterpret_cast<const float4*>(w2p + kh * 12 + 4);
            const float4 wC = *reinterpret_cast<const float4*>(w2p + kh * 12 + 8);
            const float* e0 = eS + 32 * kh;
            FMA12(a0, e0,       wA, wB, wC);
            FMA12(a1, e0 + 192, wA, wB, wC);
            FMA12(a2, e0 + 384, wA, wB, wC);
            FMA12(a3, e0 + 576, wA, wB, wC);
            if (k4) FMA12(a4, e0 + 768, wA, wB, wC);
        }
        size_t base = (size_t)NB * 288 + (size_t)gs * 288 + l;
        stF<TY>(yws, base,       a0); stF<TY>(yws, base + 64,  a1);
        stF<TY>(yws, base + 128, a2); stF<TY>(yws, base + 192, a3);
        float sum = a0 + a1 + a2 + a3;
        float sq  = fmaf(a0, a0, fmaf(a1, a1, fmaf(a2, a2, a3 * a3)));
        if (k4) { stF<TY>(yws, base + 256, a4); sum += a4; sq = fmaf(a4, a4, sq); }
        sum += __shfl_xor(sum, 16); sq += __shfl_xor(sq, 16);
        sum += __shfl_xor(sum, 32); sq += __shfl_xor(sq, 32);
        if (tg == 0) { atomicAdd(&stat_s[32 + o * 2], sum); atomicAdd(&stat_s[32 + o * 2 + 1], sq); }
    }

    // ---- ec = relu(channel-linear): SCALAR reads (2-way banks), overlay raw [t][12] ----
    {
        float* ec = rawS;
        #pragma unroll 2
        for (int j = 0; j < 8; ++j) {
            int n = l + 64 * j;               // n < 512
            int t = n / 9, d = n - 9 * t;
            float a = wl[OFF_C0B + d];
            const float* e = eT + t * 16;
            #pragma unroll
            for (int c = 0; c < 12; ++c) a = fmaf(e[c], wl[OFF_C0 + c * 9 + d], a);
            ec[t * 12 + d] = fmaxf(a, 0.f);
        }
        if (l == 0) {                          // n = 512: t=56, d=8
            float a = wl[OFF_C0B + 8];
            const float* e = eT + 56 * 16;
            #pragma unroll
            for (int c = 0; c < 12; ++c) a = fmaf(e[c], wl[OFF_C0 + c * 9 + 8], a);
            ec[56 * 12 + 8] = fmaxf(a, 0.f);
        }
    }

    // ---- tau=2: conv2d 5x9 stride (3,1).  ec-row = 36tg + 12kh + 144k ----
    {
        const float b = wl[OFF_B3 + o];
        float a0 = b, a1 = b, a2 = b, a3 = b, a4 = b;
        const float* w3p = &wl[OFF_W3 + o * 60];
        const float* eS  = rawS + 36 * tg;
        #pragma unroll 2
        for (int kh = 0; kh < 5; ++kh) {
            const float4 wA = *reinterpret_cast<const float4*>(w3p + kh * 12);
            const float4 wB = *reinterpret_cast<const float4*>(w3p + kh * 12 + 4);
            const float  w8 = (w3p + kh * 12)[8];
            const float* e0 = eS + 12 * kh;
            FMA9(a0, e0,       wA, wB, w8);
            FMA9(a1, e0 + 144, wA, wB, w8);
            FMA9(a2, e0 + 288, wA, wB, w8);
            FMA9(a3, e0 + 432, wA, wB, w8);
            if (k4) FMA9(a4, e0 + 576, wA, wB, w8);
        }
        size_t base = (size_t)2 * NB * 288 + (size_t)gs * 288 + l;
        stF<TY>(yws, base,       a0); stF<TY>(yws, base + 64,  a1);
        stF<TY>(yws, base + 128, a2); stF<TY>(yws, base + 192, a3);
        float sum = a0 + a1 + a2 + a3;
        float sq  = fmaf(a0, a0, fmaf(a1, a1, fmaf(a2, a2, a3 * a3)));
        if (k4) { stF<TY>(yws, base + 256, a4); sum += a4; sq = fmaf(a4, a4, sq); }
        sum += __shfl_xor(sum, 16); sq += __shfl_xor(sq, 16);
        sum += __shfl_xor(sum, 32); sq += __shfl_xor(sq, 32);
        if (tg == 0) { atomicAdd(&stat_s[64 + o * 2], sum); atomicAdd(&stat_s[64 + o * 2 + 1], sq); }
    }
    __syncthreads();
    if (tid < 96) atomicAdd(&stat1[(blockIdx.x & (NSLOT - 1)) * 96 + tid], stat_s[tid]);
}

// ---------------- BN finalize (stage 1 or 2) ----------------
__global__ void kBN(const float* __restrict__ statp,
                    const float* __restrict__ g0, const float* __restrict__ be0,
                    const float* __restrict__ g1, const float* __restrict__ be1,
                    const float* __restrict__ g2, const float* __restrict__ be2,
                    float nInv, float* __restrict__ bnp)
{
    int tid = threadIdx.x;
    if (tid >= 48) return;
    int tau = tid / 16, o = tid % 16;
    float sum = 0.f, sq = 0.f;
    for (int sl = 0; sl < NSLOT; ++sl) {
        sum += statp[sl * 96 + tid * 2];
        sq  += statp[sl * 96 + tid * 2 + 1];
    }
    float mean = sum * nInv;
    float var  = sq * nInv - mean * mean;
    const float* g  = (tau == 0) ? g0 : (tau == 1) ? g1 : g2;
    const float* be = (tau == 0) ? be0 : (tau == 1) ? be1 : be2;
    float scale = g[o] / sqrtf(var + EPS);
    float shift = be[o] - mean * scale;
    bnp[tid * 2]     = scale;
    bnp[tid * 2 + 1] = shift;
}

// ---------------- Kernel C: BN1+relu, second convs, BN2 stats ----------------
template<typename TY>
__global__ __launch_bounds__(256)
void kC(const TY* __restrict__ yws, const float* __restrict__ bn1,
        const float* __restrict__ t1w2, const float* __restrict__ t1b2,
        const float* __restrict__ t2w2, const float* __restrict__ t2b2,
        const float* __restrict__ c1w2, const float* __restrict__ c1b2,
        TY* __restrict__ zws, float* __restrict__ stat2)
{
    __shared__ float h_s[3][4][288];
    __shared__ float z_s[3][4][80];
    __shared__ float bnp[96];
    const int tid = threadIdx.x;
    const int s0  = blockIdx.x * 4;

    if (tid < 96) bnp[tid] = bn1[tid];
    __syncthreads();

    for (int idx = tid; idx < 3456; idx += 256) {
        int tau = idx / 1152, rem = idx % 1152, s = rem / 288, slot = rem % 288;
        int k = slot >> 6, rr = slot & 63, tg = rr >> 4, o = rr & 15;
        int t = 4 * k + tg;
        float v = ldF<TY>(yws, (size_t)tau * NB * 288 + (size_t)(s0 + s) * 288 + slot);
        h_s[tau][s][o * 18 + t] = fmaxf(fmaf(v, bnp[(tau * 16 + o) * 2], bnp[(tau * 16 + o) * 2 + 1]), 0.f);
    }
    __syncthreads();

    for (int idx = tid; idx < 960; idx += 256) {
        int tau = idx / 320, rem = idx % 320, s = rem / 80, r = rem % 80;
        int o = r / 5, t = r % 5;
        float a;
        if (tau == 0) {
            a = t1b2[o];
            for (int c = 0; c < 16; ++c) {
                const float* hp = &h_s[0][s][c * 18 + 3 * t];
                const float* wp = &t1w2[o * 96 + c * 6];
                #pragma unroll
                for (int k = 0; k < 6; ++k) a = fmaf(hp[k], wp[k], a);
            }
        } else if (tau == 1) {
            a = t2b2[o];
            for (int c = 0; c < 16; ++c) {
                const float* hp = &h_s[1][s][c * 18 + 3 * t];
                const float* wp = &t2w2[o * 48 + c * 3];
                #pragma unroll
                for (int k = 0; k < 3; ++k) a = fmaf(hp[2 * k], wp[k], a);
            }
        } else {
            a = c1b2[o];
            for (int c = 0; c < 16; ++c) {
                const float* hp = &h_s[2][s][c * 18 + 3 * t];
                const float* wp = &c1w2[o * 80 + c * 5];
                #pragma unroll
                for (int k = 0; k < 5; ++k) a = fmaf(hp[k], wp[k], a);
            }
        }
        z_s[tau][s][r] = a;
    }
    __syncthreads();

    if (tid < 96) {
        int tau = tid / 32, rem = tid % 32, o = rem >> 1, st = rem & 1;
        float acc = 0.f;
        for (int s = 0; s < 4; ++s)
            for (int t = 0; t < 5; ++t) {
                float v = z_s[tau][s][o * 5 + t];
                acc += st ? v * v : v;
            }
        atomicAdd(&stat2[(blockIdx.x & (NSLOT - 1)) * 96 + tid], acc);
    }
    for (int idx = tid; idx < 960; idx += 256) {
        int tau = idx / 320, rem = idx % 320, s = rem / 80, r = rem % 80;
        stF<TY>(zws, (size_t)tau * NB * 80 + (size_t)(s0 + s) * 80 + r, z_s[tau][s][r]);
    }
}

// ---------------- Kernel E: BN2+relu, feats, FC, tanh ----------------
template<typename TY>
__global__ __launch_bounds__(256)
void kE(const TY* __restrict__ zws, const float* __restrict__ bn2,
        const float* __restrict__ fcw, const float* __restrict__ fcb,
        float* __restrict__ out)
{
    __shared__ float fcw_s[160 * 50];
    __shared__ float feats[8][320];
    __shared__ float fcb_s[50];
    __shared__ float bnp[96];
    const int tid = threadIdx.x;
    const int s0  = blockIdx.x * 8;

    for (int idx = tid; idx < 8000; idx += 256) fcw_s[idx] = fcw[idx];
    if (tid < 50) fcb_s[tid] = fcb[tid];
    if (tid >= 64 && tid < 160) bnp[tid - 64] = bn2[tid - 64];
    __syncthreads();

    for (int idx = tid; idx < 8 * 320; idx += 256) {
        int s = idx / 320, f = idx % 320;
        int g = f / 80; int tau = (g == 3) ? 2 : g;
        int r = f % 80, o = r / 5;
        float v = ldF<TY>(zws, (size_t)tau * NB * 80 + (size_t)(s0 + s) * 80 + r);
        feats[s][f] = fmaxf(fmaf(v, bnp[(tau * 16 + o) * 2], bnp[(tau * 16 + o) * 2 + 1]), 0.f);
    }
    __syncthreads();

    float accA = 0.f, accB = 0.f;
    int sA = tid / 50, uA = tid % 50;
    int iB = tid + 256, sB = iB / 50, uB = iB % 50;
    if (tid < 400) {
        accA = fcb_s[uA];
        for (int f = 0; f < 160; ++f) accA = fmaf(feats[sA][f], fcw_s[f * 50 + uA], accA);
    }
    if (tid < 144) {
        accB = fcb_s[uB];
        for (int f = 0; f < 160; ++f) accB = fmaf(feats[sB][f], fcw_s[f * 50 + uB], accB);
    }
    __syncthreads();
    for (int idx = tid; idx < 8000; idx += 256) fcw_s[idx] = fcw[8000 + idx];
    __syncthreads();
    if (tid < 400) {
        for (int f = 0; f < 160; ++f) accA = fmaf(feats[sA][160 + f], fcw_s[f * 50 + uA], accA);
        out[(size_t)(s0 + sA) * 50 + uA] = tanhf(accA);
    }
    if (tid < 144) {
        for (int f = 0; f < 160; ++f) accB = fmaf(feats[sB][160 + f], fcw_s[f * 50 + uB], accB);
        out[(size_t)(s0 + sB) * 50 + uB] = tanhf(accB);
    }
}

// ---------------- host launcher ----------------
template<typename TY>
static void launch_all(void* const* d_in, void* d_out, void* d_ws, hipStream_t stream)
{
    const float* raw  = (const float*)d_in[0];
    const float* eegf = (const float*)d_in[1];
    const float* fgw1 = (const float*)d_in[2];
    const float* fgb1 = (const float*)d_in[3];
    const float* fgw2 = (const float*)d_in[4];
    const float* fgb2 = (const float*)d_in[5];
    const float* t1w1 = (const float*)d_in[6];
    const float* t1b1 = (const float*)d_in[7];
    const float* t1g1 = (const float*)d_in[8];
    const float* t1be1= (const float*)d_in[9];
    const float* t1w2 = (const float*)d_in[10];
    const float* t1b2 = (const float*)d_in[11];
    const float* t1g2 = (const float*)d_in[12];
    const float* t1be2= (const float*)d_in[13];
    const float* t2w1 = (const float*)d_in[14];
    const float* t2b1 = (const float*)d_in[15];
    const float* t2g1 = (const float*)d_in[16];
    const float* t2be1= (const float*)d_in[17];
    const float* t2w2 = (const float*)d_in[18];
    const float* t2b2 = (const float*)d_in[19];
    const float* t2g2 = (const float*)d_in[20];
    const float* t2be2= (const float*)d_in[21];
    const float* c0w  = (const float*)d_in[22];
    const float* c0b  = (const float*)d_in[23];
    const float* c1w1 = (const float*)d_in[24];
    const float* c1b1 = (const float*)d_in[25];
    const float* c1g1 = (const float*)d_in[26];
    const float* c1be1= (const float*)d_in[27];
    const float* c1w2 = (const float*)d_in[28];
    const float* c1b2 = (const float*)d_in[29];
    const float* c1g2 = (const float*)d_in[30];
    const float* c1be2= (const float*)d_in[31];
    const float* fcw  = (const float*)d_in[32];
    const float* fcb  = (const float*)d_in[33];

    char* ws = (char*)d_ws;
    TY* yws = (TY*)ws;
    TY* zws = (TY*)(ws + (size_t)3 * NB * 288 * sizeof(TY));
    float* stat1 = (float*)(ws + (size_t)3 * NB * 288 * sizeof(TY) + (size_t)3 * NB * 80 * sizeof(TY));
    float* stat2 = stat1 + NSLOT * 96;
    float* bn1   = stat2 + NSLOT * 96;
    float* bn2   = bn1 + 96;

    hipMemsetAsync(stat1, 0, 2 * NSLOT * 96 * sizeof(float), stream);

    kA<TY><<<NB / 4, 256, 0, stream>>>(raw, eegf, fgw1, fgb1, fgw2, fgb2,
                                       t1w1, t1b1, t2w1, t2b1, c0w, c0b, c1w1, c1b1,
                                       yws, stat1);
    kBN<<<1, 64, 0, stream>>>(stat1, t1g1, t1be1, t2g1, t2be1, c1g1, c1be1,
                              1.f / (float)((size_t)NB * 18), bn1);
    kC<TY><<<NB / 4, 256, 0, stream>>>(yws, bn1, t1w2, t1b2, t2w2, t2b2, c1w2, c1b2,
                                       zws, stat2);
    kBN<<<1, 64, 0, stream>>>(stat2, t1g2, t1be2, t2g2, t2be2, c1g2, c1be2,
                              1.f / (float)((size_t)NB * 5), bn2);
    kE<TY><<<NB / 8, 256, 0, stream>>>(zws, bn2, fcw, fcb, (float*)d_out);
}

extern "C" void kernel_launch(void* const* d_in, const int* in_sizes, int n_in,
                              void* d_out, int out_size, void* d_ws, size_t ws_size,
                              hipStream_t stream)
{
    (void)in_sizes; (void)n_in; (void)out_size;
    size_t statBytes = (2 * NSLOT * 96 + 192) * sizeof(float);
    size_t needF32 = ((size_t)3 * NB * 288 + (size_t)3 * NB * 80) * 4 + statBytes;
    if (ws_size >= needF32)
        launch_all<float>(d_in, d_out, d_ws, stream);
    else
        launch_all<bf16>(d_in, d_out, d_ws, stream);
}